// Round 10
// baseline (4868.940 us; speedup 1.0000x reference)
//
#include <hip/hip_runtime.h>
#include <hip/hip_bf16.h>
#include <hip/hip_fp16.h>

#define NF    15
#define NBF   20
#define TT    1760
#define TS    880
#define EP    64
#define ES    128
#define DF    128
#define H1    384
#define G3    1152
#define INA   896
#define JREP  11

typedef _Float16 h2v __attribute__((ext_vector_type(2)));

__device__ __forceinline__ float sigmf_(float x){ return 1.0f/(1.0f + __expf(-x)); }
__device__ __forceinline__ float tanhf_(float x){ return 2.0f/(1.0f + __expf(-2.0f*x)) - 1.0f; }
__device__ __forceinline__ h2v bc_h2(unsigned u){ return __builtin_bit_cast(h2v, u); }
__device__ __forceinline__ float fdot2_(h2v a, h2v b, float c){
#if __has_builtin(__builtin_amdgcn_fdot2)
  return __builtin_amdgcn_fdot2(a, b, c, false);
#else
  return c + (float)a[0]*(float)b[0] + (float)a[1]*(float)b[1];
#endif
}
__device__ __forceinline__ unsigned pk2_(float a, float b){
#if __has_builtin(__builtin_amdgcn_cvt_pkrtz)
  return __builtin_bit_cast(unsigned, __builtin_amdgcn_cvt_pkrtz(a, b));
#else
  unsigned lo = (unsigned)__builtin_bit_cast(unsigned short, (_Float16)a);
  unsigned hi = (unsigned)__builtin_bit_cast(unsigned short, (_Float16)b);
  return lo | (hi << 16);
#endif
}
__device__ __forceinline__ void bar_lgkm(){
  asm volatile("s_waitcnt lgkmcnt(0)" ::: "memory");
  __builtin_amdgcn_s_barrier();
  __builtin_amdgcn_sched_barrier(0);
}

// ---------------- frame-rate network: f[64][11][128] ----------------
__global__ __launch_bounds__(128) void k_frame(const float* feat, const int* periods, const float* embp,
   const float* c1w, const float* c1b, const float* c2w, const float* c2b,
   const float* f1w, const float* f1b, const float* f2w, const float* f2b, float* fout)
{
  __shared__ float cat[NF*84];
  __shared__ float x1[13*DF];
  __shared__ float x2[JREP*DF];
  int b = blockIdx.x, tid = threadIdx.x;
  for (int idx = tid; idx < NF*84; idx += 128){
    int j = idx/84, c = idx%84;
    cat[idx] = (c < NBF) ? feat[(b*NF+j)*NBF + c]
                         : embp[periods[b*NF+j]*EP + (c-NBF)];
  }
  __syncthreads();
  int o = tid;
  for (int p = 0; p < 13; ++p){
    float acc = c1b[o];
    for (int kk = 0; kk < 3; ++kk)
      for (int c = 0; c < 84; ++c)
        acc += cat[(p+kk)*84 + c] * c1w[(o*84+c)*3+kk];
    x1[p*DF+o] = tanhf_(acc);
  }
  __syncthreads();
  for (int p = 0; p < JREP; ++p){
    float acc = c2b[o];
    for (int kk = 0; kk < 3; ++kk)
      for (int c = 0; c < DF; ++c)
        acc += x1[(p+kk)*DF+c] * c2w[(o*DF+c)*3+kk];
    x2[p*DF+o] = tanhf_(acc);
  }
  __syncthreads();
  for (int p = 0; p < JREP; ++p){
    float acc = f1b[o];
    for (int c = 0; c < DF; ++c) acc += x2[p*DF+c]*f1w[o*DF+c];
    x1[p*DF+o] = tanhf_(acc);
  }
  __syncthreads();
  for (int p = 0; p < JREP; ++p){
    float acc = f2b[o];
    for (int c = 0; c < DF; ++c) acc += x1[p*DF+c]*f2w[o*DF+c];
    fout[(b*JREP+p)*DF+o] = tanhf_(acc);
  }
}

// ---------------- pack ga_whh f32 -> per-(hf,thread) uint4-contiguous f16 (j-quarter split) ------
__global__ __launch_bounds__(256) void k_wpack5(const float* whh, _Float16* wpk){
  int o = blockIdx.x*256 + threadIdx.x;        // < 442368
  int hu = o & 1;
  int c  = (o >> 1) & 3;
  int idx = o >> 3;                            // uint4 index
  int tid = idx % 768;
  int n   = (idx / 768) % 18;
  int hf  = idx / (768*18);
  int i = tid % 384, u = tid / 384;
  int gd = n*4 + c;
  int m = gd / 12, dc = gd % 12;
  int pos  = (dc % 2) + 2*(dc / 6);
  int gate = (dc % 6) >> 1;
  int j = hf*96 + u*48 + (4*m + pos)*2 + hu;
  wpk[o] = (_Float16)whh[(gate*H1 + i)*H1 + j];
}

// ---------------- GA tables: GA[k][256][1152] ----------------
__global__ __launch_bounds__(256) void k_tables(const float* wih, const float* emb, float* GA){
  __shared__ float Wl[64*129];
  int k = blockIdx.x/18, g0 = (blockIdx.x%18)*64;
  int tid = threadIdx.x;
  for (int idx = tid; idx < 64*128; idx += 256){
    int gg = idx>>7, c = idx&127;
    Wl[gg*129+c] = wih[(size_t)(g0+gg)*INA + k*128 + c];
  }
  __syncthreads();
  int vv = tid>>6, gg = tid&63;
  for (int v = vv; v < 256; v += 4){
    const float* e = emb + (size_t)v*ES;
    float acc = 0.f;
    for (int c = 0; c < 128; ++c) acc += e[c]*Wl[gg*129+c];
    GA[(size_t)(k*256+v)*G3 + g0+gg] = acc;
  }
}

// ---------------- xWrepA[b][j][1152] ----------------
__global__ __launch_bounds__(256) void k_xwrepA(const float* wih, const float* f,
                                                const float* bih, const float* bhh, float* xwA){
  __shared__ float Wl[64*129];
  int g0 = blockIdx.x*64, tid = threadIdx.x;
  for (int idx = tid; idx < 64*128; idx += 256){
    int gg = idx>>7, c = idx&127;
    Wl[gg*129+c] = wih[(size_t)(g0+gg)*INA + 768 + c];
  }
  __syncthreads();
  int vv = tid>>6, gg = tid&63; int g = g0+gg;
  float badd = bih[g] + (g < 768 ? bhh[g] : 0.f);
  for (int row = vv; row < 64*JREP; row += 4){
    const float* fr = f + (size_t)row*DF;
    float acc = badd;
    for (int c = 0; c < 128; ++c) acc += fr[c]*Wl[gg*129+c];
    xwA[(size_t)row*G3 + g] = acc;
  }
}

// ---------------- xWrepB[b][j][48] ----------------
__global__ __launch_bounds__(256) void k_xwrepB(const float* wih, const float* f,
                                                const float* bih, const float* bhh, float* xwB){
  __shared__ float Wl[48*129];
  int b = blockIdx.x, tid = threadIdx.x;
  for (int idx = tid; idx < 48*128; idx += 256){
    int r = idx>>7, c = idx&127;
    Wl[r*129+c] = wih[r*512 + 384 + c];
  }
  __syncthreads();
  for (int idx = tid; idx < JREP*48; idx += 256){
    int j = idx/48, r = idx%48;
    const float* fr = f + (size_t)(b*JREP+j)*DF;
    float acc = bih[r] + (r < 32 ? bhh[r] : 0.f);
    for (int c = 0; c < 128; ++c) acc += fr[c]*Wl[r*129+c];
    xwB[(size_t)(b*JREP+j)*48 + r] = acc;
  }
}

// ---------------- md2 embed tables: T2[tbl][256][256] ----------------
__global__ __launch_bounds__(256) void k_t2(const float* w1, const float* w2, const float* emb, float* T2){
  __shared__ float Wl[64*129];
  int tbl = blockIdx.x>>2; int c0 = (blockIdx.x&3)*64; int tid = threadIdx.x;
  const float* w = tbl ? w2 : w1;
  for (int idx = tid; idx < 64*128; idx += 256){
    int cc = idx>>7, e = idx&127;
    Wl[cc*129+e] = w[(c0+cc)*144 + 16 + e];
  }
  __syncthreads();
  int vv = tid>>6, cc = tid&63;
  for (int v = vv; v < 256; v += 4){
    const float* e = emb + (size_t)v*ES;
    float acc = 0.f;
    for (int c = 0; c < 128; ++c) acc += e[c]*Wl[cc*129+c];
    T2[tbl*65536 + v*256 + c0+cc] = acc;
  }
}

// ---------------- GRU-A scan v10: partial-forwarding, per-consumer-contiguous publish ----------------
#define LD18(n) uint4 d##n = wsrc[(size_t)(n)*768];
#define Q2(A,B,C, q2) { \
  h2v hA = hh[jb2 + (q2)*2],     h2v_hB; h2v_hB = hh[jb2 + (q2)*2 + 1]; h2v hB = h2v_hB; \
  ar = fdot2_(hA, bc_h2(A.x), ar); ar = fdot2_(hB, bc_h2(A.y), ar); \
  az = fdot2_(hA, bc_h2(A.z), az); az = fdot2_(hB, bc_h2(A.w), az); \
  an = fdot2_(hA, bc_h2(B.x), an); an = fdot2_(hB, bc_h2(B.y), an); \
  h2v hC = hh[jb2 + (q2)*2 + 2], hD = hh[jb2 + (q2)*2 + 3]; \
  ar = fdot2_(hC, bc_h2(B.z), ar); ar = fdot2_(hD, bc_h2(B.w), ar); \
  az = fdot2_(hC, bc_h2(C.x), az); az = fdot2_(hD, bc_h2(C.y), az); \
  an = fdot2_(hC, bc_h2(C.z), an); an = fdot2_(hD, bc_h2(C.w), an); }
#undef Q2
#define Q2(A,B,C, q2) { \
  h2v hA = hh[jb2 + (q2)*2],     hB = hh[jb2 + (q2)*2 + 1]; \
  ar = fdot2_(hA, bc_h2(A.x), ar); ar = fdot2_(hB, bc_h2(A.y), ar); \
  az = fdot2_(hA, bc_h2(A.z), az); az = fdot2_(hB, bc_h2(A.w), az); \
  an = fdot2_(hA, bc_h2(B.x), an); an = fdot2_(hB, bc_h2(B.y), an); \
  h2v hC = hh[jb2 + (q2)*2 + 2], hD = hh[jb2 + (q2)*2 + 3]; \
  ar = fdot2_(hC, bc_h2(B.z), ar); ar = fdot2_(hD, bc_h2(B.w), ar); \
  az = fdot2_(hC, bc_h2(C.x), az); az = fdot2_(hD, bc_h2(C.y), az); \
  an = fdot2_(hC, bc_h2(C.z), an); an = fdot2_(hD, bc_h2(C.w), an); }
#define DOTS12 \
  Q2(d0,d1,d2,0) Q2(d3,d4,d5,2) Q2(d6,d7,d8,4) \
  Q2(d9,d10,d11,6) Q2(d12,d13,d14,8) Q2(d15,d16,d17,10)

__global__ __launch_bounds__(768, 3) void k_scanA10(const int* __restrict__ in_data,
        const float* __restrict__ GA, const float* __restrict__ xwA,
        const uint4* __restrict__ wpk, const float* __restrict__ bhh,
        unsigned* __restrict__ g1u, unsigned* pbuf)
{
  __shared__ __align__(16) unsigned h16u[48];     // own j-quarter h(t-1): 96 rows = 48 u32
  __shared__ __align__(8)  float pg[3][2][384];   // own-quarter partials [gate][u][out-row]
  __shared__ __align__(8)  float xwb[2][G3];      // xW double buffer
  __shared__ int indr[2][8];
  const int P = blockIdx.x;
  const int b = P & 63, hf = P >> 6;
  const int tid = threadIdx.x;
  const int i  = tid % 384;                       // output row (global)
  const int u  = tid / 384;                       // j-half of own quarter
  const int jb2 = u * 24;                         // h2 base into h16u
  const int* ind_b = in_data + (size_t)b*TT*3;

  // weights: 18 uint4 (j-quarter slice), loaded once
  const uint4* wsrc = wpk + (size_t)(hf*18)*768 + tid;
  LD18(0) LD18(1) LD18(2) LD18(3) LD18(4) LD18(5) LD18(6) LD18(7) LD18(8)
  LD18(9) LD18(10) LD18(11) LD18(12) LD18(13) LD18(14) LD18(15) LD18(16) LD18(17)

  const bool isGat = (tid < 576);
  const int  c0 = 2*tid, c1 = 2*tid + 1;
  const bool isPub = (tid >= 96 && tid < 528);    // 432 lanes, 2 words each = 864
  int pubRel=0, pubL=0, pubWp=0, pubR0=0;
  if (isPub){
    int e = tid - 96;
    pubRel = e / 144; int p = e % 144;
    pubL = p / 3; pubWp = p % 3;
    int qp = (hf + 1 + pubRel) & 3;
    pubR0 = qp*96 + 2*pubL;
  }

  float hreg0 = 0.f, hreg1 = 0.f, bn0 = 0.f, bn1 = 0.f;
  if (tid < 48){
    bn0 = bhh[768 + hf*96 + 2*tid];
    bn1 = bhh[768 + hf*96 + 2*tid + 1];
    h16u[tid] = 0u;
  }
  // prologue: xwb[0] for t=0 ; indices for t=1
  if (isGat){
    float s0 = xwA[(size_t)(b*JREP)*G3 + c0];
    float s1 = xwA[(size_t)(b*JREP)*G3 + c1];
    #pragma unroll
    for (int k2 = 0; k2 < 6; ++k2){
      int v = ind_b[k2];
      s0 += GA[((size_t)k2*256 + v)*G3 + c0];
      s1 += GA[((size_t)k2*256 + v)*G3 + c1];
    }
    xwb[0][c0] = s0; xwb[0][c1] = s1;
  }
  if (tid >= 576 && tid < 582) indr[1][tid-576] = ind_b[6 + (tid-576)];

  unsigned* pbo = pbuf + ((size_t)(b*4 + hf)*2)*G3;
  // consumer sources: partner pf=(hf+k)&3, rel-slot of hf in pf's buffer = 3-k
  const unsigned* s1b = pbuf + ((size_t)(b*4 + ((hf+1)&3))*2)*G3 + 2*384 + (tid<48?tid:0)*8;
  const unsigned* s2b = pbuf + ((size_t)(b*4 + ((hf+2)&3))*2)*G3 + 1*384 + (tid<48?tid:0)*8;
  const unsigned* s3b = pbuf + ((size_t)(b*4 + ((hf+3)&3))*2)*G3 + 0*384 + (tid<48?tid:0)*8;
  const h2v* hh = (const h2v*)h16u;
  __syncthreads();

  for (int t = 0; t < TS; ++t){
    const int nb = t & 1;
    // ---- phase 1: issue xW gathers for t+1, dots on OWN h-quarter ----
    const int tp = t + 1;
    float ga0=0.f,ga1=0.f,ga2=0.f,ga3=0.f,ga4=0.f,ga5=0.f,gx0=0.f;
    float gb0=0.f,gb1=0.f,gb2=0.f,gb3=0.f,gb4=0.f,gb5=0.f,gx1=0.f;
    if (tp < TS && isGat){
      int v0=indr[tp&1][0], v1=indr[tp&1][1], v2=indr[tp&1][2];
      int v3=indr[tp&1][3], v4=indr[tp&1][4], v5=indr[tp&1][5];
      const float* xwr = xwA + ((size_t)(b*JREP) + tp/80)*G3;
      ga0 = GA[((size_t)0*256 + v0)*G3 + c0]; gb0 = GA[((size_t)0*256 + v0)*G3 + c1];
      ga1 = GA[((size_t)1*256 + v1)*G3 + c0]; gb1 = GA[((size_t)1*256 + v1)*G3 + c1];
      ga2 = GA[((size_t)2*256 + v2)*G3 + c0]; gb2 = GA[((size_t)2*256 + v2)*G3 + c1];
      ga3 = GA[((size_t)3*256 + v3)*G3 + c0]; gb3 = GA[((size_t)3*256 + v3)*G3 + c1];
      ga4 = GA[((size_t)4*256 + v4)*G3 + c0]; gb4 = GA[((size_t)4*256 + v4)*G3 + c1];
      ga5 = GA[((size_t)5*256 + v5)*G3 + c0]; gb5 = GA[((size_t)5*256 + v5)*G3 + c1];
      gx0 = xwr[c0]; gx1 = xwr[c1];
    }
    int iv = 0;
    const int stg = t + 2;
    const bool doStg = (tid >= 576 && tid < 582 && stg < TS);
    if (doStg) iv = ind_b[6*stg + (tid-576)];
    float ar=0.f, az=0.f, an=0.f;
    DOTS12
    pg[0][u][i] = ar; pg[1][u][i] = az; pg[2][u][i] = an;
    if (tp < TS && isGat){
      xwb[tp&1][c0] = ga0+ga1+ga2+ga3+ga4+ga5+gx0;
      xwb[tp&1][c1] = gb0+gb1+gb2+gb3+gb4+gb5+gx1;
    }
    if (doStg) indr[t&1][tid-576] = iv;
    bar_lgkm();
    // ---- phase 2: publish (contiguous per-consumer) ; poll + epilogue ----
    if (isPub){
      float v0 = pg[pubWp][0][pubR0]   + pg[pubWp][1][pubR0];
      float v1 = pg[pubWp][0][pubR0+1] + pg[pubWp][1][pubR0+1];
      unsigned tw0 = (__builtin_bit_cast(unsigned, v0) & 0xFFFFFC00u) | (unsigned)(t & 1023);
      unsigned tw1 = (__builtin_bit_cast(unsigned, v1) & 0xFFFFFC00u) | (unsigned)(t & 1023);
      unsigned* dst = pbo + (size_t)nb*G3 + pubRel*384 + pubL*8 + pubWp*2;
      __hip_atomic_store(dst,     tw0, __ATOMIC_RELAXED, __HIP_MEMORY_SCOPE_AGENT);
      __hip_atomic_store(dst + 1, tw1, __ATOMIC_RELAXED, __HIP_MEMORY_SCOPE_AGENT);
    }
    if (tid < 48){
      // read own partials + xW while remote partials fly
      int i0 = hf*96 + 2*tid;
      float2 o0 = *(const float2*)&pg[0][0][i0];  float2 o0b = *(const float2*)&pg[0][1][i0];
      float2 o1 = *(const float2*)&pg[1][0][i0];  float2 o1b = *(const float2*)&pg[1][1][i0];
      float2 o2 = *(const float2*)&pg[2][0][i0];  float2 o2b = *(const float2*)&pg[2][1][i0];
      float2 xr = *(const float2*)&xwb[nb][i0];
      float2 xz = *(const float2*)&xwb[nb][384 + i0];
      float2 xn = *(const float2*)&xwb[nb][768 + i0];
      const unsigned tg = (unsigned)t & 1023u;
      const unsigned* q1 = s1b + (size_t)nb*G3;
      const unsigned* q2 = s2b + (size_t)nb*G3;
      const unsigned* q3 = s3b + (size_t)nb*G3;
      uint4 A1,A2,A3; uint2 B1,B2,B3;
      bool ok;
      do {
        asm volatile(
          "global_load_dwordx4 %0, %6, off sc1\n\t"
          "global_load_dwordx2 %1, %6, off offset:16 sc1\n\t"
          "global_load_dwordx4 %2, %7, off sc1\n\t"
          "global_load_dwordx2 %3, %7, off offset:16 sc1\n\t"
          "global_load_dwordx4 %4, %8, off sc1\n\t"
          "global_load_dwordx2 %5, %8, off offset:16 sc1\n\t"
          "s_waitcnt vmcnt(0)"
          : "=&v"(A1),"=&v"(B1),"=&v"(A2),"=&v"(B2),"=&v"(A3),"=&v"(B3)
          : "v"(q1),"v"(q2),"v"(q3) : "memory");
        __builtin_amdgcn_sched_barrier(0);
        ok = ((A1.x&1023u)==tg) & ((A1.y&1023u)==tg) & ((A1.z&1023u)==tg) & ((A1.w&1023u)==tg)
           & ((B1.x&1023u)==tg) & ((B1.y&1023u)==tg)
           & ((A2.x&1023u)==tg) & ((A2.y&1023u)==tg) & ((A2.z&1023u)==tg) & ((A2.w&1023u)==tg)
           & ((B2.x&1023u)==tg) & ((B2.y&1023u)==tg)
           & ((A3.x&1023u)==tg) & ((A3.y&1023u)==tg) & ((A3.z&1023u)==tg) & ((A3.w&1023u)==tg)
           & ((B3.x&1023u)==tg) & ((B3.y&1023u)==tg);
        if (!ok) __builtin_amdgcn_s_sleep(2);
      } while (!ok);
      __builtin_amdgcn_sched_barrier(0);
      #define FV(w) __builtin_bit_cast(float, (w) & 0xFFFFFC00u)
      float R0 = o0.x + o0b.x + FV(A1.x) + FV(A2.x) + FV(A3.x) + xr.x;
      float R1 = o0.y + o0b.y + FV(A1.y) + FV(A2.y) + FV(A3.y) + xr.y;
      float Z0 = o1.x + o1b.x + FV(A1.z) + FV(A2.z) + FV(A3.z) + xz.x;
      float Z1 = o1.y + o1b.y + FV(A1.w) + FV(A2.w) + FV(A3.w) + xz.y;
      float G0 = o2.x + o2b.x + FV(B1.x) + FV(B2.x) + FV(B3.x) + bn0;
      float G1 = o2.y + o2b.y + FV(B1.y) + FV(B2.y) + FV(B3.y) + bn1;
      #undef FV
      float rr0 = sigmf_(R0), zz0 = sigmf_(Z0);
      float nn0 = tanhf_(xn.x + rr0*G0);
      float h0 = (1.f - zz0)*nn0 + zz0*hreg0; hreg0 = h0;
      float rr1 = sigmf_(R1), zz1 = sigmf_(Z1);
      float nn1 = tanhf_(xn.y + rr1*G1);
      float h1 = (1.f - zz1)*nn1 + zz1*hreg1; hreg1 = h1;
      unsigned pack = pk2_(h0, h1);
      h16u[tid] = pack;
      g1u[((size_t)b*TS + t)*192 + hf*48 + tid] = pack;
    }
    bar_lgkm();
  }
}

// ---------------- xW_B = g1 @ gb_wih[:, :384].T + xWrepB (f16 dot2, LDS-staged weights) ----------
__global__ __launch_bounds__(256) void k_xwB(const unsigned* g1u, const float* wih,
                                             const float* xwrB, float* xwB){
  __shared__ __align__(16) unsigned gl[16*194];   // 16 t × 192 h2 pairs (padded)
  __shared__ __align__(16) unsigned wl[48*194];   // 48 rows × 192 h2 pairs (padded)
  int bi = blockIdx.x; int b = bi/55; int t0 = (bi%55)*16; int tid = threadIdx.x;
  for (int idx = tid; idx < 48*192; idx += 256){
    int r = idx/192, cp = idx%192;
    wl[r*194+cp] = pk2_(wih[r*512 + 2*cp], wih[r*512 + 2*cp + 1]);
  }
  for (int idx = tid; idx < 16*192; idx += 256){
    int tt = idx/192, c = idx%192;
    gl[tt*194+c] = g1u[((size_t)b*TS + t0+tt)*192 + c];
  }
  __syncthreads();
  int rr = tid>>4, tt = tid&15;
  int t = t0+tt;
  const float* xr = xwrB + ((size_t)(b*JREP) + t/80)*48;
  const h2v* gp = (const h2v*)&gl[tt*194];
  for (int rb = 0; rb < 3; ++rb){
    int r = rb*16 + rr;
    const h2v* wp_ = (const h2v*)&wl[r*194];
    float acc = 0.f;
    #pragma unroll 8
    for (int c = 0; c < 192; ++c) acc = fdot2_(gp[c], wp_[c], acc);
    xwB[((size_t)b*TS + t)*48 + r] = acc + xr[r];
  }
}

// ---------------- GRU-B scan (tiny, prefetch-pipelined) ----------------
__global__ __launch_bounds__(64) void k_scanB(const float* xwB, const float* whh,
                                              const float* bhh, float* g2){
  __shared__ float wl[48*17];
  __shared__ float h2s[16];
  __shared__ float pre[32];
  __shared__ float xn[16], gn[16];
  int b = blockIdx.x, tid = threadIdx.x;
  for (int idx = tid; idx < 768; idx += 64) wl[(idx>>4)*17 + (idx&15)] = whh[idx];
  if (tid < 16) h2s[tid] = 0.f;
  float bn = (tid >= 32 && tid < 48) ? bhh[tid] : 0.f;
  float xw_n = (tid < 48) ? xwB[(size_t)b*TS*48 + tid] : 0.f;
  __syncthreads();
  for (int t = 0; t < TS; ++t){
    float xw = xw_n;
    if (t+1 < TS && tid < 48) xw_n = xwB[((size_t)b*TS + t+1)*48 + tid];
    if (tid < 48){
      float gh = 0.f;
      #pragma unroll
      for (int e = 0; e < 16; ++e) gh += wl[tid*17+e]*h2s[e];
      if (tid < 32) pre[tid] = xw + gh;
      else { xn[tid-32] = xw; gn[tid-32] = gh + bn; }
    }
    __syncthreads();
    if (tid < 16){
      float r = sigmf_(pre[tid]), z = sigmf_(pre[16+tid]);
      float n = tanhf_(xn[tid] + r*gn[tid]);
      float hn = (1.f - z)*n + z*h2s[tid];
      h2s[tid] = hn;
      g2[((size_t)b*TS + t)*16 + tid] = hn;
    }
    __syncthreads();
  }
}

// ---------------- mdense + output interleave ----------------
__global__ __launch_bounds__(256) void k_out(const float* g2, const int* targets, const float* T2,
    const float* m1w1, const float* m1w2, const float* m1b1, const float* m1b2,
    const float* m1f1, const float* m1f2,
    const float* m2w1, const float* m2w2, const float* m2b1, const float* m2b2,
    const float* m2f1, const float* m2f2, float* out)
{
  __shared__ float wA[256*17], wB[256*17], wC[256*17], wD[256*17];
  __shared__ float g2l[16*16];
  int bi = blockIdx.x; int b = bi/55; int t0 = (bi%55)*16; int c = threadIdx.x;
  for (int d = 0; d < 16; ++d){
    wA[c*17+d] = m1w1[c*16+d];  wB[c*17+d] = m1w2[c*16+d];
    wC[c*17+d] = m2w1[c*144+d]; wD[c*17+d] = m2w2[c*144+d];
  }
  { int tt = c>>4, d = c&15; g2l[c] = g2[((size_t)b*TS + t0+tt)*16 + d]; }
  __syncthreads();
  float b1a = m1b1[c], b2a = m1b2[c], f1a = m1f1[c], f2a = m1f2[c];
  float b1b = m2b1[c], b2b = m2b2[c], f1b = m2f1[c], f2b = m2f2[c];
  for (int tt = 0; tt < 16; ++tt){
    int t = t0+tt;
    float d1 = b1a, d2 = b2a, e1 = b1b, e2 = b2b;
    for (int d = 0; d < 16; ++d){
      float g = g2l[tt*16+d];
      d1 += g*wA[c*17+d]; d2 += g*wB[c*17+d];
      e1 += g*wC[c*17+d]; e2 += g*wD[c*17+d];
    }
    int v = targets[b*TT + 2*t];
    e1 += T2[v*256+c]; e2 += T2[65536 + v*256+c];
    float o1 = f1a*tanhf_(d1) + f2a*tanhf_(d2);
    float o2 = f1b*tanhf_(e1) + f2b*tanhf_(e2);
    size_t base = ((size_t)b*TS + t)*2*256;
    out[base + c]       = o1;
    out[base + 256 + c] = o2;
  }
}

extern "C" void kernel_launch(void* const* d_in, const int* in_sizes, int n_in,
                              void* d_out, int out_size, void* d_ws, size_t ws_size,
                              hipStream_t stream) {
  const int*   in_data = (const int*)  d_in[0];
  const float* feat    = (const float*)d_in[1];
  const int*   periods = (const int*)  d_in[2];
  const int*   targets = (const int*)  d_in[3];
  const float* embp    = (const float*)d_in[4];
  const float* embs    = (const float*)d_in[5];
  const float* c1w = (const float*)d_in[6];  const float* c1b = (const float*)d_in[7];
  const float* c2w = (const float*)d_in[8];  const float* c2b = (const float*)d_in[9];
  const float* f1w = (const float*)d_in[10]; const float* f1b = (const float*)d_in[11];
  const float* f2w = (const float*)d_in[12]; const float* f2b = (const float*)d_in[13];
  const float* ga_wih = (const float*)d_in[14]; const float* ga_whh = (const float*)d_in[15];
  const float* ga_bih = (const float*)d_in[16]; const float* ga_bhh = (const float*)d_in[17];
  const float* gb_wih = (const float*)d_in[18]; const float* gb_whh = (const float*)d_in[19];
  const float* gb_bih = (const float*)d_in[20]; const float* gb_bhh = (const float*)d_in[21];
  const float* m1w1 = (const float*)d_in[22]; const float* m1w2 = (const float*)d_in[23];
  const float* m1b1 = (const float*)d_in[24]; const float* m1b2 = (const float*)d_in[25];
  const float* m1f1 = (const float*)d_in[26]; const float* m1f2 = (const float*)d_in[27];
  const float* m2w1 = (const float*)d_in[28]; const float* m2w2 = (const float*)d_in[29];
  const float* m2b1 = (const float*)d_in[30]; const float* m2b2 = (const float*)d_in[31];
  const float* m2f1 = (const float*)d_in[32]; const float* m2f2 = (const float*)d_in[33];
  float* out = (float*)d_out;

  // workspace layout (floats)
  float* GA     = (float*)d_ws;                  // 6*256*1152     = 1,769,472
  float* xWrepA = GA     + 1769472;              // 704*1152       =   811,008
  float* xWrepB = xWrepA + 811008;               // 704*48         =    33,792
  float* fbuf   = xWrepB + 33792;                // 704*128        =    90,112
  float* xWB    = fbuf   + 90112;                // 56320*48       = 2,703,360
  float* g2buf  = xWB    + 2703360;              // 56320*16       =   901,120
  float* T2     = g2buf  + 901120;               // 2*256*256      =   131,072
  _Float16* Wpk = (_Float16*)(T2 + 131072);      // 442,368 halves
  unsigned* pbuf = (unsigned*)(Wpk + 442368);    // 64*4*2*1152 u32 = 589,824
  _Float16* g1  = (_Float16*)d_out;              // scratch inside output buffer (43.3MB < 115MB)

  (void)hipMemsetAsync(pbuf, 0xFF, 589824*sizeof(unsigned), stream);
  hipLaunchKernelGGL(k_frame, dim3(64), dim3(128), 0, stream,
                     feat, periods, embp, c1w, c1b, c2w, c2b, f1w, f1b, f2w, f2b, fbuf);
  hipLaunchKernelGGL(k_wpack5, dim3(1728), dim3(256), 0, stream, ga_whh, Wpk);
  hipLaunchKernelGGL(k_tables, dim3(108), dim3(256), 0, stream, ga_wih, embs, GA);
  hipLaunchKernelGGL(k_t2, dim3(8), dim3(256), 0, stream, m2w1, m2w2, embs, T2);
  hipLaunchKernelGGL(k_xwrepA, dim3(18), dim3(256), 0, stream, ga_wih, fbuf, ga_bih, ga_bhh, xWrepA);
  hipLaunchKernelGGL(k_xwrepB, dim3(64), dim3(256), 0, stream, gb_wih, fbuf, gb_bih, gb_bhh, xWrepB);
  hipLaunchKernelGGL(k_scanA10, dim3(256), dim3(768), 0, stream,
                     in_data, GA, xWrepA, (const uint4*)Wpk, ga_bhh,
                     (unsigned*)g1, pbuf);
  hipLaunchKernelGGL(k_xwB, dim3(64*55), dim3(256), 0, stream,
                     (const unsigned*)g1, gb_wih, xWrepB, xWB);
  hipLaunchKernelGGL(k_scanB, dim3(64), dim3(64), 0, stream, xWB, gb_whh, gb_bhh, g2buf);
  hipLaunchKernelGGL(k_out, dim3(64*55), dim3(256), 0, stream,
                     g2buf, targets, T2, m1w1, m1w2, m1b1, m1b2, m1f1, m1f2,
                     m2w1, m2w2, m2b1, m2b2, m2f1, m2f2, out);
}

// Round 11
// 4164.726 us; speedup vs baseline: 1.1691x; 1.1691x over previous
//
#include <hip/hip_runtime.h>
#include <hip/hip_bf16.h>
#include <hip/hip_fp16.h>

#define NF    15
#define NBF   20
#define TT    1760
#define TS    880
#define EP    64
#define ES    128
#define DF    128
#define H1    384
#define G3    1152
#define INA   896
#define JREP  11

typedef _Float16 h2v __attribute__((ext_vector_type(2)));

__device__ __forceinline__ float sigmf_(float x){ return 1.0f/(1.0f + __expf(-x)); }
__device__ __forceinline__ float tanhf_(float x){ return 2.0f/(1.0f + __expf(-2.0f*x)) - 1.0f; }
__device__ __forceinline__ h2v bc_h2(unsigned u){ return __builtin_bit_cast(h2v, u); }
__device__ __forceinline__ float fdot2_(h2v a, h2v b, float c){
#if __has_builtin(__builtin_amdgcn_fdot2)
  return __builtin_amdgcn_fdot2(a, b, c, false);
#else
  return c + (float)a[0]*(float)b[0] + (float)a[1]*(float)b[1];
#endif
}
__device__ __forceinline__ unsigned pk2_(float a, float b){
#if __has_builtin(__builtin_amdgcn_cvt_pkrtz)
  return __builtin_bit_cast(unsigned, __builtin_amdgcn_cvt_pkrtz(a, b));
#else
  unsigned lo = (unsigned)__builtin_bit_cast(unsigned short, (_Float16)a);
  unsigned hi = (unsigned)__builtin_bit_cast(unsigned short, (_Float16)b);
  return lo | (hi << 16);
#endif
}
__device__ __forceinline__ void bar_lgkm(){
  asm volatile("s_waitcnt lgkmcnt(0)" ::: "memory");
  __builtin_amdgcn_s_barrier();
  __builtin_amdgcn_sched_barrier(0);
}

// ---------------- frame-rate network: f[64][11][128] ----------------
__global__ __launch_bounds__(128) void k_frame(const float* feat, const int* periods, const float* embp,
   const float* c1w, const float* c1b, const float* c2w, const float* c2b,
   const float* f1w, const float* f1b, const float* f2w, const float* f2b, float* fout)
{
  __shared__ float cat[NF*84];
  __shared__ float x1[13*DF];
  __shared__ float x2[JREP*DF];
  int b = blockIdx.x, tid = threadIdx.x;
  for (int idx = tid; idx < NF*84; idx += 128){
    int j = idx/84, c = idx%84;
    cat[idx] = (c < NBF) ? feat[(b*NF+j)*NBF + c]
                         : embp[periods[b*NF+j]*EP + (c-NBF)];
  }
  __syncthreads();
  int o = tid;
  for (int p = 0; p < 13; ++p){
    float acc = c1b[o];
    for (int kk = 0; kk < 3; ++kk)
      for (int c = 0; c < 84; ++c)
        acc += cat[(p+kk)*84 + c] * c1w[(o*84+c)*3+kk];
    x1[p*DF+o] = tanhf_(acc);
  }
  __syncthreads();
  for (int p = 0; p < JREP; ++p){
    float acc = c2b[o];
    for (int kk = 0; kk < 3; ++kk)
      for (int c = 0; c < DF; ++c)
        acc += x1[(p+kk)*DF+c] * c2w[(o*DF+c)*3+kk];
    x2[p*DF+o] = tanhf_(acc);
  }
  __syncthreads();
  for (int p = 0; p < JREP; ++p){
    float acc = f1b[o];
    for (int c = 0; c < DF; ++c) acc += x2[p*DF+c]*f1w[o*DF+c];
    x1[p*DF+o] = tanhf_(acc);
  }
  __syncthreads();
  for (int p = 0; p < JREP; ++p){
    float acc = f2b[o];
    for (int c = 0; c < DF; ++c) acc += x1[p*DF+c]*f2w[o*DF+c];
    fout[(b*JREP+p)*DF+o] = tanhf_(acc);
  }
}

// ---------------- pack ga_whh f32 -> per-(hf,thread) uint4-contiguous f16 (j-quarter split) ------
__global__ __launch_bounds__(256) void k_wpack5(const float* whh, _Float16* wpk){
  int o = blockIdx.x*256 + threadIdx.x;        // < 442368
  int hu = o & 1;
  int c  = (o >> 1) & 3;
  int idx = o >> 3;                            // uint4 index
  int tid = idx % 768;
  int n   = (idx / 768) % 18;
  int hf  = idx / (768*18);
  int i = tid % 384, u = tid / 384;
  int gd = n*4 + c;
  int m = gd / 12, dc = gd % 12;
  int pos  = (dc % 2) + 2*(dc / 6);
  int gate = (dc % 6) >> 1;
  int j = hf*96 + u*48 + (4*m + pos)*2 + hu;
  wpk[o] = (_Float16)whh[(gate*H1 + i)*H1 + j];
}

// ---------------- GA tables: GA[k][256][1152] ----------------
__global__ __launch_bounds__(256) void k_tables(const float* wih, const float* emb, float* GA){
  __shared__ float Wl[64*129];
  int k = blockIdx.x/18, g0 = (blockIdx.x%18)*64;
  int tid = threadIdx.x;
  for (int idx = tid; idx < 64*128; idx += 256){
    int gg = idx>>7, c = idx&127;
    Wl[gg*129+c] = wih[(size_t)(g0+gg)*INA + k*128 + c];
  }
  __syncthreads();
  int vv = tid>>6, gg = tid&63;
  for (int v = vv; v < 256; v += 4){
    const float* e = emb + (size_t)v*ES;
    float acc = 0.f;
    for (int c = 0; c < 128; ++c) acc += e[c]*Wl[gg*129+c];
    GA[(size_t)(k*256+v)*G3 + g0+gg] = acc;
  }
}

// ---------------- xWrepA[b][j][1152] ----------------
__global__ __launch_bounds__(256) void k_xwrepA(const float* wih, const float* f,
                                                const float* bih, const float* bhh, float* xwA){
  __shared__ float Wl[64*129];
  int g0 = blockIdx.x*64, tid = threadIdx.x;
  for (int idx = tid; idx < 64*128; idx += 256){
    int gg = idx>>7, c = idx&127;
    Wl[gg*129+c] = wih[(size_t)(g0+gg)*INA + 768 + c];
  }
  __syncthreads();
  int vv = tid>>6, gg = tid&63; int g = g0+gg;
  float badd = bih[g] + (g < 768 ? bhh[g] : 0.f);
  for (int row = vv; row < 64*JREP; row += 4){
    const float* fr = f + (size_t)row*DF;
    float acc = badd;
    for (int c = 0; c < 128; ++c) acc += fr[c]*Wl[gg*129+c];
    xwA[(size_t)row*G3 + g] = acc;
  }
}

// ---------------- xWrepB[b][j][48] ----------------
__global__ __launch_bounds__(256) void k_xwrepB(const float* wih, const float* f,
                                                const float* bih, const float* bhh, float* xwB){
  __shared__ float Wl[48*129];
  int b = blockIdx.x, tid = threadIdx.x;
  for (int idx = tid; idx < 48*128; idx += 256){
    int r = idx>>7, c = idx&127;
    Wl[r*129+c] = wih[r*512 + 384 + c];
  }
  __syncthreads();
  for (int idx = tid; idx < JREP*48; idx += 256){
    int j = idx/48, r = idx%48;
    const float* fr = f + (size_t)(b*JREP+j)*DF;
    float acc = bih[r] + (r < 32 ? bhh[r] : 0.f);
    for (int c = 0; c < 128; ++c) acc += fr[c]*Wl[r*129+c];
    xwB[(size_t)(b*JREP+j)*48 + r] = acc;
  }
}

// ---------------- md2 embed tables: T2[tbl][256][256] ----------------
__global__ __launch_bounds__(256) void k_t2(const float* w1, const float* w2, const float* emb, float* T2){
  __shared__ float Wl[64*129];
  int tbl = blockIdx.x>>2; int c0 = (blockIdx.x&3)*64; int tid = threadIdx.x;
  const float* w = tbl ? w2 : w1;
  for (int idx = tid; idx < 64*128; idx += 256){
    int cc = idx>>7, e = idx&127;
    Wl[cc*129+e] = w[(c0+cc)*144 + 16 + e];
  }
  __syncthreads();
  int vv = tid>>6, cc = tid&63;
  for (int v = vv; v < 256; v += 4){
    const float* e = emb + (size_t)v*ES;
    float acc = 0.f;
    for (int c = 0; c < 128; ++c) acc += e[c]*Wl[cc*129+c];
    T2[tbl*65536 + v*256 + c0+cc] = acc;
  }
}

// ---------------- GRU-A scan v11: R9 structure + same-XCD L2 fast path (probe-elected) ----------
#define LD18(n) uint4 d##n = wsrc[(size_t)(n)*768];
#define Q2(A,B,C, q2) { \
  h2v hA = hh[jb2 + (q2)*2],     hB = hh[jb2 + (q2)*2 + 1]; \
  ar = fdot2_(hA, bc_h2(A.x), ar); ar = fdot2_(hB, bc_h2(A.y), ar); \
  az = fdot2_(hA, bc_h2(A.z), az); az = fdot2_(hB, bc_h2(A.w), az); \
  an = fdot2_(hA, bc_h2(B.x), an); an = fdot2_(hB, bc_h2(B.y), an); \
  h2v hC = hh[jb2 + (q2)*2 + 2], hD = hh[jb2 + (q2)*2 + 3]; \
  ar = fdot2_(hC, bc_h2(B.z), ar); ar = fdot2_(hD, bc_h2(B.w), ar); \
  az = fdot2_(hC, bc_h2(C.x), az); az = fdot2_(hD, bc_h2(C.y), az); \
  an = fdot2_(hC, bc_h2(C.z), an); an = fdot2_(hD, bc_h2(C.w), an); }
#define DOTS12 \
  Q2(d0,d1,d2,0) Q2(d3,d4,d5,2) Q2(d6,d7,d8,4) \
  Q2(d9,d10,d11,6) Q2(d12,d13,d14,8) Q2(d15,d16,d17,10)

#define PLW(n, p) { unsigned w = __hip_atomic_load((p), __ATOMIC_RELAXED, __HIP_MEMORY_SCOPE_AGENT); \
                    rv##n = w; ok &= ((w & 1023u) == tg); }

__global__ __launch_bounds__(768, 3) void k_scanA11(const int* __restrict__ in_data,
        const float* __restrict__ GA, const float* __restrict__ xwA,
        const uint4* __restrict__ wpk, const float* __restrict__ bhh,
        unsigned* __restrict__ g1u, unsigned* pbuf, unsigned* pbufF, int* probeF)
{
  __shared__ __align__(16) unsigned h16u[48];     // own j-quarter h(t-1): 96 rows = 48 u32
  __shared__ __align__(8)  float pg[3][2][384];   // own-quarter partials [gate][u][out-row]
  __shared__ __align__(8)  float xwb[2][G3];      // xW double buffer
  __shared__ int indr[2][8];
  __shared__ int fastFlag;
  const int P = blockIdx.x;
  const int b = P & 63, hf = P >> 6;
  const int tid = threadIdx.x;
  const int i  = tid % 384;                       // output row (global)
  const int u  = tid / 384;                       // j-half of own quarter
  const int jb2 = u * 24;                         // h2 base into h16u
  const int* ind_b = in_data + (size_t)b*TT*3;

  // weights: 18 uint4 (j-quarter slice), loaded once
  const uint4* wsrc = wpk + (size_t)(hf*18)*768 + tid;
  LD18(0) LD18(1) LD18(2) LD18(3) LD18(4) LD18(5) LD18(6) LD18(7) LD18(8)
  LD18(9) LD18(10) LD18(11) LD18(12) LD18(13) LD18(14) LD18(15) LD18(16) LD18(17)

  // ---- same-XCD fast-path election via bounded visibility probe ----
  if (tid == 0){
    unsigned s = 0x5A5A5A5Au;
    asm volatile("global_store_dword %0, %1, off sc0" :: "v"(probeF + P), "v"(s) : "memory");
    int pk = ((hf+1)&3)*64 + b;                   // one partner (all partners ≡ b mod 8)
    int seen = 0;
    for (int it = 0; it < 2000 && !seen; ++it){
      int v;
      asm volatile("global_load_dword %0, %1, off sc0\n\ts_waitcnt vmcnt(0)"
                   : "=v"(v) : "v"(probeF + pk) : "memory");
      if (v == (int)0x5A5A5A5Au) seen = 1;
      else __builtin_amdgcn_s_sleep(2);
    }
    fastFlag = seen;
  }

  const bool isGat = (tid < 576);
  const int  c0 = 2*tid, c1 = 2*tid + 1;
  const bool isPub = (tid >= 96 && tid < 672);
  const int  po0 = 2*(tid - 96);

  float hreg0 = 0.f, hreg1 = 0.f, bn0 = 0.f, bn1 = 0.f;
  if (tid < 48){
    bn0 = bhh[768 + hf*96 + 2*tid];
    bn1 = bhh[768 + hf*96 + 2*tid + 1];
    h16u[tid] = 0u;
  }
  // prologue: xwb[0] for t=0 ; indices for t=1
  if (isGat){
    float s0 = xwA[(size_t)(b*JREP)*G3 + c0];
    float s1 = xwA[(size_t)(b*JREP)*G3 + c1];
    #pragma unroll
    for (int k2 = 0; k2 < 6; ++k2){
      int v = ind_b[k2];
      s0 += GA[((size_t)k2*256 + v)*G3 + c0];
      s1 += GA[((size_t)k2*256 + v)*G3 + c1];
    }
    xwb[0][c0] = s0; xwb[0][c1] = s1;
  }
  if (tid >= 576 && tid < 582) indr[1][tid-576] = ind_b[6 + (tid-576)];

  unsigned* pbo  = pbuf  + ((size_t)(b*4 + hf)*2)*G3;
  unsigned* pboF = pbufF + ((size_t)(b*4 + hf)*2)*G3;
  const int lidx = (tid < 48 ? tid : 0);
  const unsigned* pb1  = pbuf  + ((size_t)(b*4 + ((hf+1)&3))*2)*G3 + hf*96 + 2*lidx;
  const unsigned* pb2  = pbuf  + ((size_t)(b*4 + ((hf+2)&3))*2)*G3 + hf*96 + 2*lidx;
  const unsigned* pb3  = pbuf  + ((size_t)(b*4 + ((hf+3)&3))*2)*G3 + hf*96 + 2*lidx;
  const unsigned* pb1F = pbufF + ((size_t)(b*4 + ((hf+1)&3))*2)*G3 + hf*96 + 2*lidx;
  const unsigned* pb2F = pbufF + ((size_t)(b*4 + ((hf+2)&3))*2)*G3 + hf*96 + 2*lidx;
  const unsigned* pb3F = pbufF + ((size_t)(b*4 + ((hf+3)&3))*2)*G3 + hf*96 + 2*lidx;
  const h2v* hh = (const h2v*)h16u;
  __syncthreads();
  bool myFast = (fastFlag != 0);

  for (int t = 0; t < TS; ++t){
    const int nb = t & 1;
    // ---- phase 1: issue xW gathers for t+1, dots on OWN h-quarter ----
    const int tp = t + 1;
    float ga0=0.f,ga1=0.f,ga2=0.f,ga3=0.f,ga4=0.f,ga5=0.f,gx0=0.f;
    float gb0=0.f,gb1=0.f,gb2=0.f,gb3=0.f,gb4=0.f,gb5=0.f,gx1=0.f;
    if (tp < TS && isGat){
      int v0=indr[tp&1][0], v1=indr[tp&1][1], v2=indr[tp&1][2];
      int v3=indr[tp&1][3], v4=indr[tp&1][4], v5=indr[tp&1][5];
      const float* xwr = xwA + ((size_t)(b*JREP) + tp/80)*G3;
      ga0 = GA[((size_t)0*256 + v0)*G3 + c0]; gb0 = GA[((size_t)0*256 + v0)*G3 + c1];
      ga1 = GA[((size_t)1*256 + v1)*G3 + c0]; gb1 = GA[((size_t)1*256 + v1)*G3 + c1];
      ga2 = GA[((size_t)2*256 + v2)*G3 + c0]; gb2 = GA[((size_t)2*256 + v2)*G3 + c1];
      ga3 = GA[((size_t)3*256 + v3)*G3 + c0]; gb3 = GA[((size_t)3*256 + v3)*G3 + c1];
      ga4 = GA[((size_t)4*256 + v4)*G3 + c0]; gb4 = GA[((size_t)4*256 + v4)*G3 + c1];
      ga5 = GA[((size_t)5*256 + v5)*G3 + c0]; gb5 = GA[((size_t)5*256 + v5)*G3 + c1];
      gx0 = xwr[c0]; gx1 = xwr[c1];
    }
    int iv = 0;
    const int stg = t + 2;
    const bool doStg = (tid >= 576 && tid < 582 && stg < TS);
    if (doStg) iv = ind_b[6*stg + (tid-576)];
    float ar=0.f, az=0.f, an=0.f;
    DOTS12
    pg[0][u][i] = ar; pg[1][u][i] = az; pg[2][u][i] = an;
    if (tp < TS && isGat){
      xwb[tp&1][c0] = ga0+ga1+ga2+ga3+ga4+ga5+gx0;
      xwb[tp&1][c1] = gb0+gb1+gb2+gb3+gb4+gb5+gx1;
    }
    if (doStg) indr[t&1][tid-576] = iv;
    bar_lgkm();
    // ---- phase 2: dual publish ; poll (fast-bounded then slow) + epilogue ----
    if (isPub){
      int g = po0/384, ii = po0 - g*384;
      float2 p0 = *(const float2*)&pg[g][0][ii];
      float2 p1 = *(const float2*)&pg[g][1][ii];
      float v0 = p0.x + p1.x, v1 = p0.y + p1.y;
      unsigned tw0 = (__builtin_bit_cast(unsigned, v0) & 0xFFFFFC00u) | (unsigned)(t & 1023);
      unsigned tw1 = (__builtin_bit_cast(unsigned, v1) & 0xFFFFFC00u) | (unsigned)(t & 1023);
      uint2 twv; twv.x = tw0; twv.y = tw1;
      unsigned* dstF = pboF + (size_t)nb*G3 + po0;
      asm volatile("global_store_dwordx2 %0, %1, off sc0" :: "v"(dstF), "v"(twv) : "memory");
      unsigned* dst = pbo + (size_t)nb*G3 + po0;
      __hip_atomic_store(dst,     tw0, __ATOMIC_RELAXED, __HIP_MEMORY_SCOPE_AGENT);
      __hip_atomic_store(dst + 1, tw1, __ATOMIC_RELAXED, __HIP_MEMORY_SCOPE_AGENT);
    }
    if (tid < 48){
      // read own partials + xW while remote partials fly
      int i0 = hf*96 + 2*tid;
      float2 o0 = *(const float2*)&pg[0][0][i0];  float2 o0b = *(const float2*)&pg[0][1][i0];
      float2 o1 = *(const float2*)&pg[1][0][i0];  float2 o1b = *(const float2*)&pg[1][1][i0];
      float2 o2 = *(const float2*)&pg[2][0][i0];  float2 o2b = *(const float2*)&pg[2][1][i0];
      float2 xr = *(const float2*)&xwb[nb][i0];
      float2 xz = *(const float2*)&xwb[nb][384 + i0];
      float2 xn = *(const float2*)&xwb[nb][768 + i0];
      const unsigned tg = (unsigned)t & 1023u;
      unsigned rv0,rv1,rv2,rv3,rv4,rv5,rv6,rv7,rv8;
      unsigned rv9,rv10,rv11,rv12,rv13,rv14,rv15,rv16,rv17;
      bool got = false;
      if (myFast){
        const unsigned* q1 = pb1F + (size_t)nb*G3;
        const unsigned* q2 = pb2F + (size_t)nb*G3;
        const unsigned* q3 = pb3F + (size_t)nb*G3;
        for (int att = 0; att < 32 && !got; ++att){
          uint2 F10,F11,F12,F20,F21,F22,F30,F31,F32;
          asm volatile(
            "global_load_dwordx2 %0, %9, off sc0\n\t"
            "global_load_dwordx2 %1, %9, off offset:1536 sc0\n\t"
            "global_load_dwordx2 %2, %9, off offset:3072 sc0\n\t"
            "global_load_dwordx2 %3, %10, off sc0\n\t"
            "global_load_dwordx2 %4, %10, off offset:1536 sc0\n\t"
            "global_load_dwordx2 %5, %10, off offset:3072 sc0\n\t"
            "global_load_dwordx2 %6, %11, off sc0\n\t"
            "global_load_dwordx2 %7, %11, off offset:1536 sc0\n\t"
            "global_load_dwordx2 %8, %11, off offset:3072 sc0\n\t"
            "s_waitcnt vmcnt(0)"
            : "=&v"(F10),"=&v"(F11),"=&v"(F12),"=&v"(F20),"=&v"(F21),"=&v"(F22),
              "=&v"(F30),"=&v"(F31),"=&v"(F32)
            : "v"(q1),"v"(q2),"v"(q3) : "memory");
          __builtin_amdgcn_sched_barrier(0);
          bool ok = ((F10.x&1023u)==tg)&((F10.y&1023u)==tg)&((F11.x&1023u)==tg)&((F11.y&1023u)==tg)
                  & ((F12.x&1023u)==tg)&((F12.y&1023u)==tg)
                  & ((F20.x&1023u)==tg)&((F20.y&1023u)==tg)&((F21.x&1023u)==tg)&((F21.y&1023u)==tg)
                  & ((F22.x&1023u)==tg)&((F22.y&1023u)==tg)
                  & ((F30.x&1023u)==tg)&((F30.y&1023u)==tg)&((F31.x&1023u)==tg)&((F31.y&1023u)==tg)
                  & ((F32.x&1023u)==tg)&((F32.y&1023u)==tg);
          if (ok){
            rv0=F10.x; rv1=F10.y; rv2=F11.x; rv3=F11.y; rv4=F12.x; rv5=F12.y;
            rv6=F20.x; rv7=F20.y; rv8=F21.x; rv9=F21.y; rv10=F22.x; rv11=F22.y;
            rv12=F30.x; rv13=F30.y; rv14=F31.x; rv15=F31.y; rv16=F32.x; rv17=F32.y;
            got = true;
          } else __builtin_amdgcn_s_sleep(2);
        }
        if (!got) myFast = false;   // systematic failure -> stop trying fast path
      }
      if (!got){
        const unsigned* q1 = pb1 + (size_t)nb*G3;
        const unsigned* q2 = pb2 + (size_t)nb*G3;
        const unsigned* q3 = pb3 + (size_t)nb*G3;
        bool ok;
        do {
          ok = true;
          PLW(0,  q1+0) PLW(1,  q1+1) PLW(2,  q1+384) PLW(3,  q1+385) PLW(4,  q1+768) PLW(5,  q1+769)
          PLW(6,  q2+0) PLW(7,  q2+1) PLW(8,  q2+384) PLW(9,  q2+385) PLW(10, q2+768) PLW(11, q2+769)
          PLW(12, q3+0) PLW(13, q3+1) PLW(14, q3+384) PLW(15, q3+385) PLW(16, q3+768) PLW(17, q3+769)
          if (!ok) __builtin_amdgcn_s_sleep(1);
        } while (!ok);
      }
      __builtin_amdgcn_sched_barrier(0);
      #define FVV(n) __builtin_bit_cast(float, rv##n & 0xFFFFFC00u)
      float R0 = o0.x + o0b.x + FVV(0)  + FVV(6)  + FVV(12) + xr.x;
      float R1 = o0.y + o0b.y + FVV(1)  + FVV(7)  + FVV(13) + xr.y;
      float Z0 = o1.x + o1b.x + FVV(2)  + FVV(8)  + FVV(14) + xz.x;
      float Z1 = o1.y + o1b.y + FVV(3)  + FVV(9)  + FVV(15) + xz.y;
      float G0 = o2.x + o2b.x + FVV(4)  + FVV(10) + FVV(16) + bn0;
      float G1 = o2.y + o2b.y + FVV(5)  + FVV(11) + FVV(17) + bn1;
      #undef FVV
      float rr0 = sigmf_(R0), zz0 = sigmf_(Z0);
      float nn0 = tanhf_(xn.x + rr0*G0);
      float h0 = (1.f - zz0)*nn0 + zz0*hreg0; hreg0 = h0;
      float rr1 = sigmf_(R1), zz1 = sigmf_(Z1);
      float nn1 = tanhf_(xn.y + rr1*G1);
      float h1 = (1.f - zz1)*nn1 + zz1*hreg1; hreg1 = h1;
      unsigned pack = pk2_(h0, h1);
      h16u[tid] = pack;
      g1u[((size_t)b*TS + t)*192 + hf*48 + tid] = pack;
    }
    bar_lgkm();
  }
}

// ---------------- xW_B = g1 @ gb_wih[:, :384].T + xWrepB (f16 dot2, LDS-staged weights) ----------
__global__ __launch_bounds__(256) void k_xwB(const unsigned* g1u, const float* wih,
                                             const float* xwrB, float* xwB){
  __shared__ __align__(16) unsigned gl[16*194];   // 16 t × 192 h2 pairs (padded)
  __shared__ __align__(16) unsigned wl[48*194];   // 48 rows × 192 h2 pairs (padded)
  int bi = blockIdx.x; int b = bi/55; int t0 = (bi%55)*16; int tid = threadIdx.x;
  for (int idx = tid; idx < 48*192; idx += 256){
    int r = idx/192, cp = idx%192;
    wl[r*194+cp] = pk2_(wih[r*512 + 2*cp], wih[r*512 + 2*cp + 1]);
  }
  for (int idx = tid; idx < 16*192; idx += 256){
    int tt = idx/192, c = idx%192;
    gl[tt*194+c] = g1u[((size_t)b*TS + t0+tt)*192 + c];
  }
  __syncthreads();
  int rr = tid>>4, tt = tid&15;
  int t = t0+tt;
  const float* xr = xwrB + ((size_t)(b*JREP) + t/80)*48;
  const h2v* gp = (const h2v*)&gl[tt*194];
  for (int rb = 0; rb < 3; ++rb){
    int r = rb*16 + rr;
    const h2v* wp_ = (const h2v*)&wl[r*194];
    float acc = 0.f;
    #pragma unroll 8
    for (int c = 0; c < 192; ++c) acc = fdot2_(gp[c], wp_[c], acc);
    xwB[((size_t)b*TS + t)*48 + r] = acc + xr[r];
  }
}

// ---------------- GRU-B scan (tiny, prefetch-pipelined) ----------------
__global__ __launch_bounds__(64) void k_scanB(const float* xwB, const float* whh,
                                              const float* bhh, float* g2){
  __shared__ float wl[48*17];
  __shared__ float h2s[16];
  __shared__ float pre[32];
  __shared__ float xn[16], gn[16];
  int b = blockIdx.x, tid = threadIdx.x;
  for (int idx = tid; idx < 768; idx += 64) wl[(idx>>4)*17 + (idx&15)] = whh[idx];
  if (tid < 16) h2s[tid] = 0.f;
  float bn = (tid >= 32 && tid < 48) ? bhh[tid] : 0.f;
  float xw_n = (tid < 48) ? xwB[(size_t)b*TS*48 + tid] : 0.f;
  __syncthreads();
  for (int t = 0; t < TS; ++t){
    float xw = xw_n;
    if (t+1 < TS && tid < 48) xw_n = xwB[((size_t)b*TS + t+1)*48 + tid];
    if (tid < 48){
      float gh = 0.f;
      #pragma unroll
      for (int e = 0; e < 16; ++e) gh += wl[tid*17+e]*h2s[e];
      if (tid < 32) pre[tid] = xw + gh;
      else { xn[tid-32] = xw; gn[tid-32] = gh + bn; }
    }
    __syncthreads();
    if (tid < 16){
      float r = sigmf_(pre[tid]), z = sigmf_(pre[16+tid]);
      float n = tanhf_(xn[tid] + r*gn[tid]);
      float hn = (1.f - z)*n + z*h2s[tid];
      h2s[tid] = hn;
      g2[((size_t)b*TS + t)*16 + tid] = hn;
    }
    __syncthreads();
  }
}

// ---------------- mdense + output interleave ----------------
__global__ __launch_bounds__(256) void k_out(const float* g2, const int* targets, const float* T2,
    const float* m1w1, const float* m1w2, const float* m1b1, const float* m1b2,
    const float* m1f1, const float* m1f2,
    const float* m2w1, const float* m2w2, const float* m2b1, const float* m2b2,
    const float* m2f1, const float* m2f2, float* out)
{
  __shared__ float wA[256*17], wB[256*17], wC[256*17], wD[256*17];
  __shared__ float g2l[16*16];
  int bi = blockIdx.x; int b = bi/55; int t0 = (bi%55)*16; int c = threadIdx.x;
  for (int d = 0; d < 16; ++d){
    wA[c*17+d] = m1w1[c*16+d];  wB[c*17+d] = m1w2[c*16+d];
    wC[c*17+d] = m2w1[c*144+d]; wD[c*17+d] = m2w2[c*144+d];
  }
  { int tt = c>>4, d = c&15; g2l[c] = g2[((size_t)b*TS + t0+tt)*16 + d]; }
  __syncthreads();
  float b1a = m1b1[c], b2a = m1b2[c], f1a = m1f1[c], f2a = m1f2[c];
  float b1b = m2b1[c], b2b = m2b2[c], f1b = m2f1[c], f2b = m2f2[c];
  for (int tt = 0; tt < 16; ++tt){
    int t = t0+tt;
    float d1 = b1a, d2 = b2a, e1 = b1b, e2 = b2b;
    for (int d = 0; d < 16; ++d){
      float g = g2l[tt*16+d];
      d1 += g*wA[c*17+d]; d2 += g*wB[c*17+d];
      e1 += g*wC[c*17+d]; e2 += g*wD[c*17+d];
    }
    int v = targets[b*TT + 2*t];
    e1 += T2[v*256+c]; e2 += T2[65536 + v*256+c];
    float o1 = f1a*tanhf_(d1) + f2a*tanhf_(d2);
    float o2 = f1b*tanhf_(e1) + f2b*tanhf_(e2);
    size_t base = ((size_t)b*TS + t)*2*256;
    out[base + c]       = o1;
    out[base + 256 + c] = o2;
  }
}

extern "C" void kernel_launch(void* const* d_in, const int* in_sizes, int n_in,
                              void* d_out, int out_size, void* d_ws, size_t ws_size,
                              hipStream_t stream) {
  const int*   in_data = (const int*)  d_in[0];
  const float* feat    = (const float*)d_in[1];
  const int*   periods = (const int*)  d_in[2];
  const int*   targets = (const int*)  d_in[3];
  const float* embp    = (const float*)d_in[4];
  const float* embs    = (const float*)d_in[5];
  const float* c1w = (const float*)d_in[6];  const float* c1b = (const float*)d_in[7];
  const float* c2w = (const float*)d_in[8];  const float* c2b = (const float*)d_in[9];
  const float* f1w = (const float*)d_in[10]; const float* f1b = (const float*)d_in[11];
  const float* f2w = (const float*)d_in[12]; const float* f2b = (const float*)d_in[13];
  const float* ga_wih = (const float*)d_in[14]; const float* ga_whh = (const float*)d_in[15];
  const float* ga_bih = (const float*)d_in[16]; const float* ga_bhh = (const float*)d_in[17];
  const float* gb_wih = (const float*)d_in[18]; const float* gb_whh = (const float*)d_in[19];
  const float* gb_bih = (const float*)d_in[20]; const float* gb_bhh = (const float*)d_in[21];
  const float* m1w1 = (const float*)d_in[22]; const float* m1w2 = (const float*)d_in[23];
  const float* m1b1 = (const float*)d_in[24]; const float* m1b2 = (const float*)d_in[25];
  const float* m1f1 = (const float*)d_in[26]; const float* m1f2 = (const float*)d_in[27];
  const float* m2w1 = (const float*)d_in[28]; const float* m2w2 = (const float*)d_in[29];
  const float* m2b1 = (const float*)d_in[30]; const float* m2b2 = (const float*)d_in[31];
  const float* m2f1 = (const float*)d_in[32]; const float* m2f2 = (const float*)d_in[33];
  float* out = (float*)d_out;

  // workspace layout (floats)
  float* GA     = (float*)d_ws;                  // 6*256*1152     = 1,769,472
  float* xWrepA = GA     + 1769472;              // 704*1152       =   811,008
  float* xWrepB = xWrepA + 811008;               // 704*48         =    33,792
  float* fbuf   = xWrepB + 33792;                // 704*128        =    90,112
  float* xWB    = fbuf   + 90112;                // 56320*48       = 2,703,360
  float* g2buf  = xWB    + 2703360;              // 56320*16       =   901,120
  float* T2     = g2buf  + 901120;               // 2*256*256      =   131,072
  _Float16* Wpk = (_Float16*)(T2 + 131072);      // 442,368 halves
  unsigned* pbuf  = (unsigned*)(Wpk + 442368);   // 64*4*2*1152 u32 = 589,824
  unsigned* pbufF = pbuf + 589824;               // 589,824 u32
  int* probeF     = (int*)(pbufF + 589824);      // 256 ints
  _Float16* g1  = (_Float16*)d_out;              // scratch inside output buffer (43.3MB < 115MB)

  (void)hipMemsetAsync(pbuf, 0xFF, 589824*sizeof(unsigned), stream);
  (void)hipMemsetAsync(pbufF, 0xFF, 589824*sizeof(unsigned), stream);
  (void)hipMemsetAsync(probeF, 0, 256*sizeof(int), stream);
  hipLaunchKernelGGL(k_frame, dim3(64), dim3(128), 0, stream,
                     feat, periods, embp, c1w, c1b, c2w, c2b, f1w, f1b, f2w, f2b, fbuf);
  hipLaunchKernelGGL(k_wpack5, dim3(1728), dim3(256), 0, stream, ga_whh, Wpk);
  hipLaunchKernelGGL(k_tables, dim3(108), dim3(256), 0, stream, ga_wih, embs, GA);
  hipLaunchKernelGGL(k_t2, dim3(8), dim3(256), 0, stream, m2w1, m2w2, embs, T2);
  hipLaunchKernelGGL(k_xwrepA, dim3(18), dim3(256), 0, stream, ga_wih, fbuf, ga_bih, ga_bhh, xWrepA);
  hipLaunchKernelGGL(k_xwrepB, dim3(64), dim3(256), 0, stream, gb_wih, fbuf, gb_bih, gb_bhh, xWrepB);
  hipLaunchKernelGGL(k_scanA11, dim3(256), dim3(768), 0, stream,
                     in_data, GA, xWrepA, (const uint4*)Wpk, ga_bhh,
                     (unsigned*)g1, pbuf, pbufF, probeF);
  hipLaunchKernelGGL(k_xwB, dim3(64*55), dim3(256), 0, stream,
                     (const unsigned*)g1, gb_wih, xWrepB, xWB);
  hipLaunchKernelGGL(k_scanB, dim3(64), dim3(64), 0, stream, xWB, gb_whh, gb_bhh, g2buf);
  hipLaunchKernelGGL(k_out, dim3(64*55), dim3(256), 0, stream,
                     g2buf, targets, T2, m1w1, m1w2, m1b1, m1b2, m1f1, m1f2,
                     m2w1, m2w2, m2b1, m2b2, m2f1, m2f2, out);
}